// Round 5
// baseline (1004.233 us; speedup 1.0000x reference)
//
#include <hip/hip_runtime.h>
#include <math.h>

#define NF 128      // feature/hidden dim (F == H == 128)
#define TROWS 32    // fused-kernel tile rows (16 KB LDS)

typedef float v4f __attribute__((ext_vector_type(4)));
__device__ inline void nt_store4(float* p, float4 v) {
    v4f t; t.x = v.x; t.y = v.y; t.z = v.z; t.w = v.w;
    __builtin_nontemporal_store(t, (v4f*)p);
}

// ---------- setup kernels ----------

__global__ void k_deg(const int* __restrict__ ei, int* cnt, int E) {
    int e = blockIdx.x * blockDim.x + threadIdx.x;
    if (e < E) atomicAdd(&cnt[ei[E + e]], 1);   // dst row; cnt = deg w/o self-loop
}

// Block-level exclusive scan over (cnt+1), also emits dinv = rsqrt(deg+1).
__global__ void k_scan1(const int* __restrict__ cnt, float* dinv,
                        int* offs, int* bsum, int n) {
    __shared__ int s[256];
    int t = threadIdx.x;
    int i = blockIdx.x * 256 + t;
    int v = 0;
    if (i < n) {
        v = cnt[i] + 1;                 // +1 self-loop
        dinv[i] = 1.0f / sqrtf((float)v);
    }
    s[t] = v;
    for (int d = 1; d < 256; d <<= 1) {
        __syncthreads();
        int add = (t >= d) ? s[t - d] : 0;
        __syncthreads();
        s[t] += add;
    }
    __syncthreads();
    if (i < n) offs[i] = s[t] - v;          // exclusive
    if (t == 255) bsum[blockIdx.x] = s[255]; // block total
}

// Single-block exclusive scan of block sums (nb <= 512).
__global__ void k_scan2(int* bsum, int nb) {
    __shared__ int s[512];
    int t = threadIdx.x;
    int v = (t < nb) ? bsum[t] : 0;
    s[t] = v;
    for (int d = 1; d < 512; d <<= 1) {
        __syncthreads();
        int add = (t >= d) ? s[t - d] : 0;
        __syncthreads();
        s[t] += add;
    }
    __syncthreads();
    if (t < nb) bsum[t] = s[t] - v;         // exclusive
}

__global__ void k_scan3(int* offs, const int* __restrict__ bsum, int* cursor, int n, int total) {
    int i = blockIdx.x * 256 + threadIdx.x;
    if (i < n) {
        int o = offs[i] + bsum[blockIdx.x];
        offs[i] = o;
        cursor[i] = o;
    }
    if (i == 0) offs[n] = total;
}

// Scatter edge srcs (+ self loops) into dst-sorted CSR (index only; norm is
// factored into the q-representation of h).
__global__ void k_fill(const int* __restrict__ ei, int* cursor, int* srcS, int E, int n) {
    int t = blockIdx.x * blockDim.x + threadIdx.x;
    if (t < E) {
        int s = ei[t], d = ei[E + t];
        int p = atomicAdd(&cursor[d], 1);
        srcS[p] = s;
    } else if (t < E + n) {
        int i = t - E;
        int p = atomicAdd(&cursor[i], 1);
        srcS[p] = i;
    }
}

// q0 = dinv[i] * x[i][:]  (elementwise, float4)
__global__ void k_scale(const float* __restrict__ x, const float* __restrict__ dinv,
                        float* __restrict__ q, int total4) {
    int i = blockIdx.x * blockDim.x + threadIdx.x;
    if (i >= total4) return;
    float4 v = ((const float4*)x)[i];
    float d = dinv[i >> 5];              // NF/4 = 32 float4 per row
    v.x *= d; v.y *= d; v.z *= d; v.w *= d;
    ((float4*)q)[i] = v;
}

// ---------- fused layer: gather-sum into LDS tile, then GEMM+bias+ReLU ----------
// q-formulation: hin holds q = dinv*h. agg[d] = dinv[d] * sum_e q[src].
// Layers 0-2 write q_out = dinv*relu(...); last layer writes plain h.
// Gather: 8 groups x 4 rows, float4/lane, edges unrolled x8 (pure adds).
// GEMM: As reads broadcast within 32-lane group (conflict-free, no pad).
__global__ __launch_bounds__(256, 6) void k_fused(
        const float* __restrict__ hin, const int* __restrict__ offs,
        const int* __restrict__ srcS, const float* __restrict__ dinv,
        const float* __restrict__ W, const float* __restrict__ bias,
        float* __restrict__ out, int n, int ntiles, int last) {
    __shared__ float As[TROWS * NF];
    int tid = threadIdx.x;
    int grp = tid >> 5;          // 0..7
    int c4 = (tid & 31) << 2;    // float4 column offset

    for (int tile = blockIdx.x; tile < ntiles; tile += gridDim.x) {
        int row0 = tile * TROWS;

        // ---- gather/sum phase ----
        #pragma unroll
        for (int i = 0; i < 4; ++i) {
            int r = grp * 4 + i;
            int node = row0 + r;
            float4 acc = make_float4(0.f, 0.f, 0.f, 0.f);
            if (node < n) {
                int b = offs[node], e = offs[node + 1];
                int j = b;
                for (; j + 8 <= e; j += 8) {
                    int s0 = srcS[j],     s1 = srcS[j + 1], s2 = srcS[j + 2], s3 = srcS[j + 3];
                    int s4 = srcS[j + 4], s5 = srcS[j + 5], s6 = srcS[j + 6], s7 = srcS[j + 7];
                    float4 r0 = *(const float4*)(hin + (size_t)s0 * NF + c4);
                    float4 r1 = *(const float4*)(hin + (size_t)s1 * NF + c4);
                    float4 r2 = *(const float4*)(hin + (size_t)s2 * NF + c4);
                    float4 r3 = *(const float4*)(hin + (size_t)s3 * NF + c4);
                    float4 r4 = *(const float4*)(hin + (size_t)s4 * NF + c4);
                    float4 r5 = *(const float4*)(hin + (size_t)s5 * NF + c4);
                    float4 r6 = *(const float4*)(hin + (size_t)s6 * NF + c4);
                    float4 r7 = *(const float4*)(hin + (size_t)s7 * NF + c4);
                    acc.x += ((r0.x + r1.x) + (r2.x + r3.x)) + ((r4.x + r5.x) + (r6.x + r7.x));
                    acc.y += ((r0.y + r1.y) + (r2.y + r3.y)) + ((r4.y + r5.y) + (r6.y + r7.y));
                    acc.z += ((r0.z + r1.z) + (r2.z + r3.z)) + ((r4.z + r5.z) + (r6.z + r7.z));
                    acc.w += ((r0.w + r1.w) + (r2.w + r3.w)) + ((r4.w + r5.w) + (r6.w + r7.w));
                }
                for (; j + 4 <= e; j += 4) {
                    int s0 = srcS[j], s1 = srcS[j + 1], s2 = srcS[j + 2], s3 = srcS[j + 3];
                    float4 r0 = *(const float4*)(hin + (size_t)s0 * NF + c4);
                    float4 r1 = *(const float4*)(hin + (size_t)s1 * NF + c4);
                    float4 r2 = *(const float4*)(hin + (size_t)s2 * NF + c4);
                    float4 r3 = *(const float4*)(hin + (size_t)s3 * NF + c4);
                    acc.x += (r0.x + r1.x) + (r2.x + r3.x);
                    acc.y += (r0.y + r1.y) + (r2.y + r3.y);
                    acc.z += (r0.z + r1.z) + (r2.z + r3.z);
                    acc.w += (r0.w + r1.w) + (r2.w + r3.w);
                }
                for (; j < e; ++j) {
                    int s = srcS[j];
                    float4 rr = *(const float4*)(hin + (size_t)s * NF + c4);
                    acc.x += rr.x; acc.y += rr.y; acc.z += rr.z; acc.w += rr.w;
                }
                float dn = dinv[node];
                acc.x *= dn; acc.y *= dn; acc.z *= dn; acc.w *= dn;
            }
            *(float4*)(As + r * NF + c4) = acc;
        }
        __syncthreads();

        // ---- GEMM + bias + ReLU (+ dinv rescale for non-last layers) ----
        float4 acc[4];
        #pragma unroll
        for (int j = 0; j < 4; ++j) acc[j] = make_float4(0.f, 0.f, 0.f, 0.f);

        const float* Wp = W + c4;
        const float* Ap = As + grp * 4 * NF;
        for (int k = 0; k < 128; k += 4) {
            float4 w0 = *(const float4*)(Wp + (k + 0) * NF);
            float4 w1 = *(const float4*)(Wp + (k + 1) * NF);
            float4 w2 = *(const float4*)(Wp + (k + 2) * NF);
            float4 w3 = *(const float4*)(Wp + (k + 3) * NF);
            #pragma unroll
            for (int j = 0; j < 4; ++j) {
                float4 a = *(const float4*)(Ap + j * NF + k);
                acc[j].x += a.x * w0.x + a.y * w1.x + a.z * w2.x + a.w * w3.x;
                acc[j].y += a.x * w0.y + a.y * w1.y + a.z * w2.y + a.w * w3.y;
                acc[j].z += a.x * w0.z + a.y * w1.z + a.z * w2.z + a.w * w3.z;
                acc[j].w += a.x * w0.w + a.y * w1.w + a.z * w2.w + a.w * w3.w;
            }
        }

        float4 bv = *(const float4*)(bias + c4);
        #pragma unroll
        for (int j = 0; j < 4; ++j) {
            int gr = row0 + grp * 4 + j;
            if (gr < n) {
                float sc = last ? 1.0f : dinv[gr];
                float4 o;
                o.x = fmaxf(acc[j].x + bv.x, 0.f) * sc;
                o.y = fmaxf(acc[j].y + bv.y, 0.f) * sc;
                o.z = fmaxf(acc[j].z + bv.z, 0.f) * sc;
                o.w = fmaxf(acc[j].w + bv.w, 0.f) * sc;
                nt_store4(out + (size_t)gr * NF + c4, o);
            }
        }
        __syncthreads();   // As reused next tile
    }
}

// ---------- fused pool + head (batch sorted -> contiguous ranges; bounds inline) ----------

__global__ __launch_bounds__(256) void k_poolfinal(const float* __restrict__ h,
        const int* __restrict__ batch, const float* __restrict__ linW,
        const float* __restrict__ linb, float* __restrict__ outp, int N) {
    int g = blockIdx.x;
    int tid = threadIdx.x;
    __shared__ int sb[2];
    if (tid < 2) {                       // lower_bound(batch, g+tid)
        int target = g + tid;
        int lo = 0, hi = N;
        while (lo < hi) {
            int mid = (lo + hi) >> 1;
            if (batch[mid] < target) lo = mid + 1; else hi = mid;
        }
        sb[tid] = lo;
    }
    __syncthreads();
    int b = sb[0], e = sb[1];

    int grp = tid >> 5, c4 = (tid & 31) << 2;
    float4 acc = make_float4(0.f, 0.f, 0.f, 0.f);
    for (int i = b + grp; i < e; i += 8) {
        float4 v = *(const float4*)(h + (size_t)i * NF + c4);
        acc.x += v.x; acc.y += v.y; acc.z += v.z; acc.w += v.w;
    }
    __shared__ float red[8][NF];
    *(float4*)(&red[grp][c4]) = acc;
    __syncthreads();

    float v0 = 0.f, v1 = 0.f;
    if (tid < NF) {
        float s = 0.f;
        #pragma unroll
        for (int gg = 0; gg < 8; ++gg) s += red[gg][tid];
        v0 = s * linW[tid * 2 + 0];
        v1 = s * linW[tid * 2 + 1];
    }
    #pragma unroll
    for (int d = 32; d > 0; d >>= 1) {
        v0 += __shfl_down(v0, d);
        v1 += __shfl_down(v1, d);
    }
    __shared__ float sv[8];
    if ((tid & 63) == 0) { sv[(tid >> 6) * 2] = v0; sv[(tid >> 6) * 2 + 1] = v1; }
    __syncthreads();
    if (tid == 0) {
        float inv = 1.0f / fmaxf((float)(e - b), 1.0f);
        outp[g * 2 + 0] = (sv[0] + sv[2]) * inv + linb[0];
        outp[g * 2 + 1] = (sv[1] + sv[3]) * inv + linb[1];
    }
}

// ---------- launcher ----------

extern "C" void kernel_launch(void* const* d_in, const int* in_sizes, int n_in,
                              void* d_out, int out_size, void* d_ws, size_t ws_size,
                              hipStream_t stream) {
    const float* x     = (const float*)d_in[0];
    const int*   ei    = (const int*)d_in[1];
    const int*   batch = (const int*)d_in[2];
    const float* Wl[4] = {(const float*)d_in[3], (const float*)d_in[5],
                          (const float*)d_in[7], (const float*)d_in[9]};
    const float* bl[4] = {(const float*)d_in[4], (const float*)d_in[6],
                          (const float*)d_in[8], (const float*)d_in[10]};
    const float* linW  = (const float*)d_in[11];
    const float* linb  = (const float*)d_in[12];
    float* out = (float*)d_out;

    const int N  = in_sizes[2];
    const int E  = in_sizes[1] / 2;
    const int G  = out_size / 2;
    const int Et = E + N;

    // carve workspace (256B-aligned slices)
    char* p = (char*)d_ws;
    auto carve = [&](size_t bytes) -> char* {
        char* r = p;
        p += (bytes + 255) & ~(size_t)255;
        return r;
    };
    int*   cnt    = (int*)  carve((size_t)N * 4);
    float* dinv   = (float*)carve((size_t)N * 4);
    int*   offs   = (int*)  carve((size_t)(N + 1) * 4);
    int*   cursor = (int*)  carve((size_t)N * 4);
    int*   bsum   = (int*)  carve(512 * 4);
    int*   srcS   = (int*)  carve((size_t)Et * 4);
    float* bufA   = (float*)carve((size_t)N * NF * 4);   // ping
    float* bufB   = (float*)carve((size_t)N * NF * 4);   // pong

    hipMemsetAsync(cnt, 0, (size_t)N * 4, stream);
    k_deg<<<(E + 255) / 256, 256, 0, stream>>>(ei, cnt, E);

    int nb = (N + 255) / 256;   // 391 <= 512
    k_scan1<<<nb, 256, 0, stream>>>(cnt, dinv, offs, bsum, N);
    k_scan2<<<1, 512, 0, stream>>>(bsum, nb);
    k_scan3<<<nb, 256, 0, stream>>>(offs, bsum, cursor, N, Et);
    k_fill<<<(Et + 255) / 256, 256, 0, stream>>>(ei, cursor, srcS, E, N);

    int total4 = N * NF / 4;
    k_scale<<<(total4 + 255) / 256, 256, 0, stream>>>(x, dinv, bufA, total4);

    int ntiles = (N + TROWS - 1) / TROWS;
    int ngrid = ntiles < 2048 ? ntiles : 2048;
    const float* hin = bufA;
    float* hout = bufB;
    for (int l = 0; l < 4; ++l) {
        k_fused<<<ngrid, 256, 0, stream>>>(hin, offs, srcS, dinv, Wl[l], bl[l],
                                           hout, N, ntiles, l == 3);
        hin = hout;
        hout = (hout == bufA) ? bufB : bufA;
    }

    k_poolfinal<<<G, 256, 0, stream>>>((const float*)hin, batch, linW, linb, out, N);
}

// Round 6
// 996.921 us; speedup vs baseline: 1.0073x; 1.0073x over previous
//
#include <hip/hip_runtime.h>
#include <math.h>

#define NF 128      // feature/hidden dim (F == H == 128)
#define TROWS 32    // fused-kernel tile rows (16 KB LDS)

typedef float v4f __attribute__((ext_vector_type(4)));
__device__ inline void nt_store4(float* p, float4 v) {
    v4f t; t.x = v.x; t.y = v.y; t.z = v.z; t.w = v.w;
    __builtin_nontemporal_store(t, (v4f*)p);
}

// ---------- setup kernels ----------

__global__ void k_deg(const int* __restrict__ ei, int* cnt, int E) {
    int e = blockIdx.x * blockDim.x + threadIdx.x;
    if (e < E) atomicAdd(&cnt[ei[E + e]], 1);   // dst row; cnt = deg w/o self-loop
}

// Exclusive scan over PADDED counts vpad = roundup(cnt+1, 4); item n has v=0 so
// offs[n] lands automatically. Also emits dinv = rsqrt(real deg).
__global__ void k_scan1(const int* __restrict__ cnt, float* dinv,
                        int* offs, int* bsum, int n) {
    __shared__ int s[256];
    int t = threadIdx.x;
    int i = blockIdx.x * 256 + t;
    int v = 0;
    if (i < n) {
        int real = cnt[i] + 1;          // +1 self-loop
        dinv[i] = 1.0f / sqrtf((float)real);
        v = (real + 3) & ~3;            // pad row to multiple of 4
    }
    s[t] = v;
    for (int d = 1; d < 256; d <<= 1) {
        __syncthreads();
        int add = (t >= d) ? s[t - d] : 0;
        __syncthreads();
        s[t] += add;
    }
    __syncthreads();
    if (i <= n) offs[i] = s[t] - v;          // exclusive
    if (t == 255) bsum[blockIdx.x] = s[255]; // block total
}

// Single-block exclusive scan of block sums (nb <= 512).
__global__ void k_scan2(int* bsum, int nb) {
    __shared__ int s[512];
    int t = threadIdx.x;
    int v = (t < nb) ? bsum[t] : 0;
    s[t] = v;
    for (int d = 1; d < 512; d <<= 1) {
        __syncthreads();
        int add = (t >= d) ? s[t - d] : 0;
        __syncthreads();
        s[t] += add;
    }
    __syncthreads();
    if (t < nb) bsum[t] = s[t] - v;         // exclusive
}

__global__ void k_scan3(int* offs, const int* __restrict__ bsum, int* cursor, int n) {
    int i = blockIdx.x * 256 + threadIdx.x;
    if (i <= n) {
        int o = offs[i] + bsum[blockIdx.x];
        offs[i] = o;
        cursor[i] = o;
    }
}

// One prep kernel:
//  (a) q0[row] = dinv[row] * x[row]  (row n -> zeros; sentinel row)
//  (b) scatter real edges into padded dst-sorted CSR via atomic cursor
//      (slots [offs[d], offs[d]+cnt[d])), self-loop + sentinel padding at end
//  (c) zero the 4 per-layer tile counters
__global__ void k_prep(const int* __restrict__ ei, const float* __restrict__ x,
                       const float* __restrict__ dinv, const int* __restrict__ cnt,
                       const int* __restrict__ offs, int* cursor, int* srcS,
                       float* __restrict__ q, int* ctr, int E, int n) {
    int t = blockIdx.x * blockDim.x + threadIdx.x;
    if (t < 4) ctr[t] = 0;
    int total4 = (n + 1) * (NF / 4);
    if (t < total4) {
        int row = t >> 5;                 // NF/4 = 32 float4 per row
        float4 v = make_float4(0.f, 0.f, 0.f, 0.f);
        if (row < n) {
            v = ((const float4*)x)[t];
            float d = dinv[row];
            v.x *= d; v.y *= d; v.z *= d; v.w *= d;
        }
        ((float4*)q)[t] = v;
    }
    if (t < E) {
        int s = ei[t], d = ei[E + t];
        int p = atomicAdd(&cursor[d], 1);
        srcS[p] = s;
    } else if (t < E + n) {
        int i = t - E;
        int base = offs[i] + cnt[i];      // after the cnt[i] real edges
        srcS[base] = i;                   // self-loop
        int end = offs[i + 1];
        for (int k = base + 1; k < end; ++k) srcS[k] = n;   // sentinel padding
    }
}

// ---------- fused layer: gather-sum into LDS tile, then GEMM+bias+ReLU ----------
// q-formulation: hin holds q = dinv*h (row n = zeros). agg[d] = dinv[d]*sum q[src].
// Padded CSR: row counts multiple of 4, 16B-aligned -> int4 index loads, no tail.
// Dynamic tile scheduling via atomic counter (no grid-quantization tail).
__global__ __launch_bounds__(256, 8) void k_fused(
        const float* __restrict__ hin, const int* __restrict__ offs,
        const int* __restrict__ srcS, const float* __restrict__ dinv,
        const float* __restrict__ W, const float* __restrict__ bias,
        float* __restrict__ out, int n, int ntiles, int last, int* ctr) {
    __shared__ float As[TROWS * NF];
    __shared__ int stile;
    int tid = threadIdx.x;
    int grp = tid >> 5;          // 0..7
    int c4 = (tid & 31) << 2;    // float4 column offset

    for (;;) {
        if (tid == 0) stile = atomicAdd(ctr, 1);
        __syncthreads();                   // also protects As/stile from prev iter
        int tile = stile;
        if (tile >= ntiles) break;
        int row0 = tile * TROWS;

        // ---- gather/sum phase ----
        #pragma unroll
        for (int i = 0; i < 4; ++i) {
            int r = grp * 4 + i;
            int node = row0 + r;
            float4 acc = make_float4(0.f, 0.f, 0.f, 0.f);
            if (node < n) {
                int b = offs[node], e = offs[node + 1];
                int j = b;
                for (; j + 8 <= e; j += 8) {
                    int4 sa = *(const int4*)(srcS + j);
                    int4 sb = *(const int4*)(srcS + j + 4);
                    float4 r0 = *(const float4*)(hin + (size_t)sa.x * NF + c4);
                    float4 r1 = *(const float4*)(hin + (size_t)sa.y * NF + c4);
                    float4 r2 = *(const float4*)(hin + (size_t)sa.z * NF + c4);
                    float4 r3 = *(const float4*)(hin + (size_t)sa.w * NF + c4);
                    float4 r4 = *(const float4*)(hin + (size_t)sb.x * NF + c4);
                    float4 r5 = *(const float4*)(hin + (size_t)sb.y * NF + c4);
                    float4 r6 = *(const float4*)(hin + (size_t)sb.z * NF + c4);
                    float4 r7 = *(const float4*)(hin + (size_t)sb.w * NF + c4);
                    acc.x += ((r0.x + r1.x) + (r2.x + r3.x)) + ((r4.x + r5.x) + (r6.x + r7.x));
                    acc.y += ((r0.y + r1.y) + (r2.y + r3.y)) + ((r4.y + r5.y) + (r6.y + r7.y));
                    acc.z += ((r0.z + r1.z) + (r2.z + r3.z)) + ((r4.z + r5.z) + (r6.z + r7.z));
                    acc.w += ((r0.w + r1.w) + (r2.w + r3.w)) + ((r4.w + r5.w) + (r6.w + r7.w));
                }
                if (j < e) {                 // exactly 4 remain (count % 8 == 4)
                    int4 sa = *(const int4*)(srcS + j);
                    float4 r0 = *(const float4*)(hin + (size_t)sa.x * NF + c4);
                    float4 r1 = *(const float4*)(hin + (size_t)sa.y * NF + c4);
                    float4 r2 = *(const float4*)(hin + (size_t)sa.z * NF + c4);
                    float4 r3 = *(const float4*)(hin + (size_t)sa.w * NF + c4);
                    acc.x += (r0.x + r1.x) + (r2.x + r3.x);
                    acc.y += (r0.y + r1.y) + (r2.y + r3.y);
                    acc.z += (r0.z + r1.z) + (r2.z + r3.z);
                    acc.w += (r0.w + r1.w) + (r2.w + r3.w);
                }
                float dn = dinv[node];
                acc.x *= dn; acc.y *= dn; acc.z *= dn; acc.w *= dn;
            }
            *(float4*)(As + r * NF + c4) = acc;
        }
        __syncthreads();

        // ---- GEMM + bias + ReLU (+ dinv rescale for non-last layers) ----
        float4 acc[4];
        #pragma unroll
        for (int j = 0; j < 4; ++j) acc[j] = make_float4(0.f, 0.f, 0.f, 0.f);

        const float* Wp = W + c4;
        const float* Ap = As + grp * 4 * NF;
        for (int k = 0; k < 128; k += 4) {
            float4 w0 = *(const float4*)(Wp + (k + 0) * NF);
            float4 w1 = *(const float4*)(Wp + (k + 1) * NF);
            float4 w2 = *(const float4*)(Wp + (k + 2) * NF);
            float4 w3 = *(const float4*)(Wp + (k + 3) * NF);
            #pragma unroll
            for (int j = 0; j < 4; ++j) {
                float4 a = *(const float4*)(Ap + j * NF + k);
                acc[j].x += a.x * w0.x + a.y * w1.x + a.z * w2.x + a.w * w3.x;
                acc[j].y += a.x * w0.y + a.y * w1.y + a.z * w2.y + a.w * w3.y;
                acc[j].z += a.x * w0.z + a.y * w1.z + a.z * w2.z + a.w * w3.z;
                acc[j].w += a.x * w0.w + a.y * w1.w + a.z * w2.w + a.w * w3.w;
            }
        }

        float4 bv = *(const float4*)(bias + c4);
        #pragma unroll
        for (int j = 0; j < 4; ++j) {
            int gr = row0 + grp * 4 + j;
            if (gr < n) {
                float sc = last ? 1.0f : dinv[gr];
                float4 o;
                o.x = fmaxf(acc[j].x + bv.x, 0.f) * sc;
                o.y = fmaxf(acc[j].y + bv.y, 0.f) * sc;
                o.z = fmaxf(acc[j].z + bv.z, 0.f) * sc;
                o.w = fmaxf(acc[j].w + bv.w, 0.f) * sc;
                nt_store4(out + (size_t)gr * NF + c4, o);
            } else if (gr == n) {
                nt_store4(out + (size_t)gr * NF + c4,
                          make_float4(0.f, 0.f, 0.f, 0.f));   // keep sentinel row zero
            }
        }
        __syncthreads();   // As reused next tile
    }
}

// ---------- fused pool + head (batch sorted -> contiguous ranges; bounds inline) ----------

__global__ __launch_bounds__(256) void k_poolfinal(const float* __restrict__ h,
        const int* __restrict__ batch, const float* __restrict__ linW,
        const float* __restrict__ linb, float* __restrict__ outp, int N) {
    int g = blockIdx.x;
    int tid = threadIdx.x;
    __shared__ int sb[2];
    if (tid < 2) {                       // lower_bound(batch, g+tid)
        int target = g + tid;
        int lo = 0, hi = N;
        while (lo < hi) {
            int mid = (lo + hi) >> 1;
            if (batch[mid] < target) lo = mid + 1; else hi = mid;
        }
        sb[tid] = lo;
    }
    __syncthreads();
    int b = sb[0], e = sb[1];

    int grp = tid >> 5, c4 = (tid & 31) << 2;
    float4 acc = make_float4(0.f, 0.f, 0.f, 0.f);
    for (int i = b + grp; i < e; i += 8) {
        float4 v = *(const float4*)(h + (size_t)i * NF + c4);
        acc.x += v.x; acc.y += v.y; acc.z += v.z; acc.w += v.w;
    }
    __shared__ float red[8][NF];
    *(float4*)(&red[grp][c4]) = acc;
    __syncthreads();

    float v0 = 0.f, v1 = 0.f;
    if (tid < NF) {
        float s = 0.f;
        #pragma unroll
        for (int gg = 0; gg < 8; ++gg) s += red[gg][tid];
        v0 = s * linW[tid * 2 + 0];
        v1 = s * linW[tid * 2 + 1];
    }
    #pragma unroll
    for (int d = 32; d > 0; d >>= 1) {
        v0 += __shfl_down(v0, d);
        v1 += __shfl_down(v1, d);
    }
    __shared__ float sv[8];
    if ((tid & 63) == 0) { sv[(tid >> 6) * 2] = v0; sv[(tid >> 6) * 2 + 1] = v1; }
    __syncthreads();
    if (tid == 0) {
        float inv = 1.0f / fmaxf((float)(e - b), 1.0f);
        outp[g * 2 + 0] = (sv[0] + sv[2]) * inv + linb[0];
        outp[g * 2 + 1] = (sv[1] + sv[3]) * inv + linb[1];
    }
}

// ---------- launcher ----------

extern "C" void kernel_launch(void* const* d_in, const int* in_sizes, int n_in,
                              void* d_out, int out_size, void* d_ws, size_t ws_size,
                              hipStream_t stream) {
    const float* x     = (const float*)d_in[0];
    const int*   ei    = (const int*)d_in[1];
    const int*   batch = (const int*)d_in[2];
    const float* Wl[4] = {(const float*)d_in[3], (const float*)d_in[5],
                          (const float*)d_in[7], (const float*)d_in[9]};
    const float* bl[4] = {(const float*)d_in[4], (const float*)d_in[6],
                          (const float*)d_in[8], (const float*)d_in[10]};
    const float* linW  = (const float*)d_in[11];
    const float* linb  = (const float*)d_in[12];
    float* out = (float*)d_out;

    const int N  = in_sizes[2];
    const int E  = in_sizes[1] / 2;
    const int G  = out_size / 2;

    // carve workspace (256B-aligned slices)
    char* p = (char*)d_ws;
    auto carve = [&](size_t bytes) -> char* {
        char* r = p;
        p += (bytes + 255) & ~(size_t)255;
        return r;
    };
    int*   cnt    = (int*)  carve((size_t)N * 4);
    float* dinv   = (float*)carve((size_t)N * 4);
    int*   offs   = (int*)  carve((size_t)(N + 1) * 4);
    int*   cursor = (int*)  carve((size_t)(N + 1) * 4);
    int*   bsum   = (int*)  carve(512 * 4);
    int*   ctr    = (int*)  carve(4 * 4);
    int*   srcS   = (int*)  carve((size_t)(E + 4 * (size_t)N) * 4);   // padded CSR
    float* bufA   = (float*)carve((size_t)(N + 1) * NF * 4);   // ping (row N = 0)
    float* bufB   = (float*)carve((size_t)(N + 1) * NF * 4);   // pong (row N = 0)

    hipMemsetAsync(cnt, 0, (size_t)N * 4, stream);
    k_deg<<<(E + 255) / 256, 256, 0, stream>>>(ei, cnt, E);

    int nb = (N + 1 + 255) / 256;   // covers items 0..N (item N has count 0)
    k_scan1<<<nb, 256, 0, stream>>>(cnt, dinv, offs, bsum, N);
    k_scan2<<<1, 512, 0, stream>>>(bsum, nb);
    k_scan3<<<nb, 256, 0, stream>>>(offs, bsum, cursor, N);

    int total4 = (N + 1) * (NF / 4);
    int prepT = total4 > E + N ? total4 : E + N;
    k_prep<<<(prepT + 255) / 256, 256, 0, stream>>>(ei, x, dinv, cnt, offs, cursor,
                                                    srcS, bufA, ctr, E, N);

    int ntiles = (N + 1 + TROWS - 1) / TROWS;
    int ngrid = ntiles < 2048 ? ntiles : 2048;
    const float* hin = bufA;
    float* hout = bufB;
    for (int l = 0; l < 4; ++l) {
        k_fused<<<ngrid, 256, 0, stream>>>(hin, offs, srcS, dinv, Wl[l], bl[l],
                                           hout, N, ntiles, l == 3, ctr + l);
        hin = hout;
        hout = (hout == bufA) ? bufB : bufA;
    }

    k_poolfinal<<<G, 256, 0, stream>>>((const float*)hin, batch, linW, linb, out, N);
}

// Round 8
// 774.626 us; speedup vs baseline: 1.2964x; 1.2870x over previous
//
#include <hip/hip_runtime.h>
#include <math.h>

#define NF 128      // feature/hidden dim (F == H == 128)
#define NU 64       // uints per bf16 row (NF/2)
#define TROWS 32    // fused-kernel tile rows (16 KB LDS)

typedef unsigned int  u32;
typedef unsigned short u16;
typedef u32 b4 __attribute__((ext_vector_type(2)));   // 4 bf16 channels (8B)

__device__ inline u16 f2bf(float f) {               // RNE float->bf16
    u32 u = __float_as_uint(f);
    return (u16)((u + 0x7fffu + ((u >> 16) & 1u)) >> 16);
}
__device__ inline u32 pack2(float a, float b) {     // ch2k=lo, ch2k+1=hi
    return (u32)f2bf(a) | ((u32)f2bf(b) << 16);
}
__device__ inline float bflo(u32 u) { return __uint_as_float(u << 16); }
__device__ inline float bfhi(u32 u) { return __uint_as_float(u & 0xffff0000u); }

__device__ inline void nt_store_b4(u32* p, b4 v) {
    __builtin_nontemporal_store(v, (b4*)p);
}

// ---------- setup kernels ----------

__global__ void k_deg(const int* __restrict__ ei, int* cnt, int E) {
    int e = blockIdx.x * blockDim.x + threadIdx.x;
    if (e < E) atomicAdd(&cnt[ei[E + e]], 1);   // dst row; cnt = deg w/o self-loop
}

// Exclusive scan over PADDED counts vpad = roundup(cnt+1, 4); item n has v=0 so
// offs[n] lands automatically. Also emits dinv = rsqrt(real deg).
__global__ void k_scan1(const int* __restrict__ cnt, float* dinv,
                        int* offs, int* bsum, int n) {
    __shared__ int s[256];
    int t = threadIdx.x;
    int i = blockIdx.x * 256 + t;
    int v = 0;
    if (i < n) {
        int real = cnt[i] + 1;          // +1 self-loop
        dinv[i] = 1.0f / sqrtf((float)real);
        v = (real + 3) & ~3;            // pad row to multiple of 4
    }
    s[t] = v;
    for (int d = 1; d < 256; d <<= 1) {
        __syncthreads();
        int add = (t >= d) ? s[t - d] : 0;
        __syncthreads();
        s[t] += add;
    }
    __syncthreads();
    if (i <= n) offs[i] = s[t] - v;          // exclusive
    if (t == 255) bsum[blockIdx.x] = s[255]; // block total
}

__global__ void k_scan2(int* bsum, int nb) {
    __shared__ int s[512];
    int t = threadIdx.x;
    int v = (t < nb) ? bsum[t] : 0;
    s[t] = v;
    for (int d = 1; d < 512; d <<= 1) {
        __syncthreads();
        int add = (t >= d) ? s[t - d] : 0;
        __syncthreads();
        s[t] += add;
    }
    __syncthreads();
    if (t < nb) bsum[t] = s[t] - v;         // exclusive
}

__global__ void k_scan3(int* offs, const int* __restrict__ bsum, int* cursor, int n) {
    int i = blockIdx.x * 256 + threadIdx.x;
    if (i <= n) {
        int o = offs[i] + bsum[blockIdx.x];
        offs[i] = o;
        cursor[i] = o;
    }
}

// One prep kernel:
//  (a) q0[row] = bf16(dinv[row] * x[row])  (row n -> zeros; sentinel row)
//  (b) scatter real edges into padded dst-sorted CSR via atomic cursor,
//      self-loop + sentinel padding at row end
__global__ void k_prep(const int* __restrict__ ei, const float* __restrict__ x,
                       const float* __restrict__ dinv, const int* __restrict__ cnt,
                       const int* __restrict__ offs, int* cursor, int* srcS,
                       u32* __restrict__ q, int E, int n) {
    int t = blockIdx.x * blockDim.x + threadIdx.x;
    int totalu4 = (n + 1) * (NU / 4);     // 16 uint4 per row
    if (t < totalu4) {
        int row = t >> 4;
        uint4 o = make_uint4(0, 0, 0, 0);
        if (row < n) {
            int cbase = (t & 15) << 3;    // 8 channels per uint4
            const float* xr = x + (size_t)row * NF + cbase;
            float4 f0 = *(const float4*)(xr);
            float4 f1 = *(const float4*)(xr + 4);
            float d = dinv[row];
            o.x = pack2(f0.x * d, f0.y * d);
            o.y = pack2(f0.z * d, f0.w * d);
            o.z = pack2(f1.x * d, f1.y * d);
            o.w = pack2(f1.z * d, f1.w * d);
        }
        ((uint4*)q)[t] = o;
    }
    if (t < E) {
        int s = ei[t], d = ei[E + t];
        int p = atomicAdd(&cursor[d], 1);
        srcS[p] = s;
    } else if (t < E + n) {
        int i = t - E;
        int base = offs[i] + cnt[i];      // after the cnt[i] real edges
        srcS[base] = i;                   // self-loop
        int end = offs[i + 1];
        for (int k = base + 1; k < end; ++k) srcS[k] = n;   // sentinel padding
    }
}

// ---------- fused layer: bf16 gather-sum into fp32 LDS tile, then GEMM+bias+ReLU ----------
// hin: bf16 q = dinv*h (row n zeros). agg[d] = dinv[d]*sum q[src] (fp32 acc).
// Padded CSR (counts %4==0) -> int4 index loads, no tail loop.
// Output stored bf16 (q-form for layers 0-2, plain h for last).
__global__ __launch_bounds__(256, 8) void k_fused(
        const u32* __restrict__ hin, const int* __restrict__ offs,
        const int* __restrict__ srcS, const float* __restrict__ dinv,
        const float* __restrict__ W, const float* __restrict__ bias,
        u32* __restrict__ out, int n, int ntiles, int last) {
    __shared__ float As[TROWS * NF];
    int tid = threadIdx.x;
    int grp = tid >> 5;          // 0..7
    int lane = tid & 31;
    int c4 = lane << 2;          // channel offset (4 channels/lane)
    int cu = lane << 1;          // uint offset within bf16 row

    for (int tile = blockIdx.x; tile < ntiles; tile += gridDim.x) {
        int row0 = tile * TROWS;

        // ---- gather/sum phase ----
        #pragma unroll
        for (int i = 0; i < 4; ++i) {
            int r = grp * 4 + i;
            int node = row0 + r;
            float4 acc = make_float4(0.f, 0.f, 0.f, 0.f);
            if (node < n) {
                int b = offs[node], e = offs[node + 1];
                int j = b;
                for (; j + 8 <= e; j += 8) {
                    int4 sa = *(const int4*)(srcS + j);
                    int4 sb = *(const int4*)(srcS + j + 4);
                    b4 q0 = *(const b4*)(hin + (size_t)sa.x * NU + cu);
                    b4 q1 = *(const b4*)(hin + (size_t)sa.y * NU + cu);
                    b4 q2 = *(const b4*)(hin + (size_t)sa.z * NU + cu);
                    b4 q3 = *(const b4*)(hin + (size_t)sa.w * NU + cu);
                    b4 q4 = *(const b4*)(hin + (size_t)sb.x * NU + cu);
                    b4 q5 = *(const b4*)(hin + (size_t)sb.y * NU + cu);
                    b4 q6 = *(const b4*)(hin + (size_t)sb.z * NU + cu);
                    b4 q7 = *(const b4*)(hin + (size_t)sb.w * NU + cu);
                    acc.x += ((bflo(q0.x) + bflo(q1.x)) + (bflo(q2.x) + bflo(q3.x)))
                           + ((bflo(q4.x) + bflo(q5.x)) + (bflo(q6.x) + bflo(q7.x)));
                    acc.y += ((bfhi(q0.x) + bfhi(q1.x)) + (bfhi(q2.x) + bfhi(q3.x)))
                           + ((bfhi(q4.x) + bfhi(q5.x)) + (bfhi(q6.x) + bfhi(q7.x)));
                    acc.z += ((bflo(q0.y) + bflo(q1.y)) + (bflo(q2.y) + bflo(q3.y)))
                           + ((bflo(q4.y) + bflo(q5.y)) + (bflo(q6.y) + bflo(q7.y)));
                    acc.w += ((bfhi(q0.y) + bfhi(q1.y)) + (bfhi(q2.y) + bfhi(q3.y)))
                           + ((bfhi(q4.y) + bfhi(q5.y)) + (bfhi(q6.y) + bfhi(q7.y)));
                }
                if (j < e) {                 // exactly 4 remain (count % 8 == 4)
                    int4 sa = *(const int4*)(srcS + j);
                    b4 q0 = *(const b4*)(hin + (size_t)sa.x * NU + cu);
                    b4 q1 = *(const b4*)(hin + (size_t)sa.y * NU + cu);
                    b4 q2 = *(const b4*)(hin + (size_t)sa.z * NU + cu);
                    b4 q3 = *(const b4*)(hin + (size_t)sa.w * NU + cu);
                    acc.x += (bflo(q0.x) + bflo(q1.x)) + (bflo(q2.x) + bflo(q3.x));
                    acc.y += (bfhi(q0.x) + bfhi(q1.x)) + (bfhi(q2.x) + bfhi(q3.x));
                    acc.z += (bflo(q0.y) + bflo(q1.y)) + (bflo(q2.y) + bflo(q3.y));
                    acc.w += (bfhi(q0.y) + bfhi(q1.y)) + (bfhi(q2.y) + bfhi(q3.y));
                }
                float dn = dinv[node];
                acc.x *= dn; acc.y *= dn; acc.z *= dn; acc.w *= dn;
            }
            *(float4*)(As + r * NF + c4) = acc;
        }
        __syncthreads();

        // ---- GEMM + bias + ReLU (+ dinv rescale for non-last layers) ----
        float4 acc[4];
        #pragma unroll
        for (int j = 0; j < 4; ++j) acc[j] = make_float4(0.f, 0.f, 0.f, 0.f);

        const float* Wp = W + c4;
        const float* Ap = As + grp * 4 * NF;
        for (int k = 0; k < 128; k += 4) {
            float4 w0 = *(const float4*)(Wp + (k + 0) * NF);
            float4 w1 = *(const float4*)(Wp + (k + 1) * NF);
            float4 w2 = *(const float4*)(Wp + (k + 2) * NF);
            float4 w3 = *(const float4*)(Wp + (k + 3) * NF);
            #pragma unroll
            for (int j = 0; j < 4; ++j) {
                float4 a = *(const float4*)(Ap + j * NF + k);
                acc[j].x += a.x * w0.x + a.y * w1.x + a.z * w2.x + a.w * w3.x;
                acc[j].y += a.x * w0.y + a.y * w1.y + a.z * w2.y + a.w * w3.y;
                acc[j].z += a.x * w0.z + a.y * w1.z + a.z * w2.z + a.w * w3.z;
                acc[j].w += a.x * w0.w + a.y * w1.w + a.z * w2.w + a.w * w3.w;
            }
        }

        float4 bv = *(const float4*)(bias + c4);
        #pragma unroll
        for (int j = 0; j < 4; ++j) {
            int gr = row0 + grp * 4 + j;
            if (gr <= n) {
                b4 o; o.x = 0u; o.y = 0u;
                if (gr < n) {
                    float sc = last ? 1.0f : dinv[gr];
                    float ox = fmaxf(acc[j].x + bv.x, 0.f) * sc;
                    float oy = fmaxf(acc[j].y + bv.y, 0.f) * sc;
                    float oz = fmaxf(acc[j].z + bv.z, 0.f) * sc;
                    float ow = fmaxf(acc[j].w + bv.w, 0.f) * sc;
                    o.x = pack2(ox, oy);
                    o.y = pack2(oz, ow);
                }
                nt_store_b4(out + (size_t)gr * NU + cu, o);   // gr==n keeps sentinel 0
            }
        }
        __syncthreads();   // As reused next tile
    }
}

// ---------- fused pool + head (batch sorted -> contiguous ranges; bounds inline) ----------

__global__ __launch_bounds__(256) void k_poolfinal(const u32* __restrict__ h,
        const int* __restrict__ batch, const float* __restrict__ linW,
        const float* __restrict__ linb, float* __restrict__ outp, int N) {
    int g = blockIdx.x;
    int tid = threadIdx.x;
    __shared__ int sb[2];
    if (tid < 2) {                       // lower_bound(batch, g+tid)
        int target = g + tid;
        int lo = 0, hi = N;
        while (lo < hi) {
            int mid = (lo + hi) >> 1;
            if (batch[mid] < target) lo = mid + 1; else hi = mid;
        }
        sb[tid] = lo;
    }
    __syncthreads();
    int b = sb[0], e = sb[1];

    int grp = tid >> 5, lane = tid & 31;
    int c4 = lane << 2, cu = lane << 1;
    float4 acc = make_float4(0.f, 0.f, 0.f, 0.f);
    for (int i = b + grp; i < e; i += 8) {
        b4 v = *(const b4*)(h + (size_t)i * NU + cu);
        acc.x += bflo(v.x); acc.y += bfhi(v.x);
        acc.z += bflo(v.y); acc.w += bfhi(v.y);
    }
    __shared__ float red[8][NF];
    *(float4*)(&red[grp][c4]) = acc;
    __syncthreads();

    float v0 = 0.f, v1 = 0.f;
    if (tid < NF) {
        float s = 0.f;
        #pragma unroll
        for (int gg = 0; gg < 8; ++gg) s += red[gg][tid];
        v0 = s * linW[tid * 2 + 0];
        v1 = s * linW[tid * 2 + 1];
    }
    #pragma unroll
    for (int d = 32; d > 0; d >>= 1) {
        v0 += __shfl_down(v0, d);
        v1 += __shfl_down(v1, d);
    }
    __shared__ float sv[8];
    if ((tid & 63) == 0) { sv[(tid >> 6) * 2] = v0; sv[(tid >> 6) * 2 + 1] = v1; }
    __syncthreads();
    if (tid == 0) {
        float inv = 1.0f / fmaxf((float)(e - b), 1.0f);
        outp[g * 2 + 0] = (sv[0] + sv[2]) * inv + linb[0];
        outp[g * 2 + 1] = (sv[1] + sv[3]) * inv + linb[1];
    }
}

// ---------- launcher ----------

extern "C" void kernel_launch(void* const* d_in, const int* in_sizes, int n_in,
                              void* d_out, int out_size, void* d_ws, size_t ws_size,
                              hipStream_t stream) {
    const float* x     = (const float*)d_in[0];
    const int*   ei    = (const int*)d_in[1];
    const int*   batch = (const int*)d_in[2];
    const float* Wl[4] = {(const float*)d_in[3], (const float*)d_in[5],
                          (const float*)d_in[7], (const float*)d_in[9]};
    const float* bl[4] = {(const float*)d_in[4], (const float*)d_in[6],
                          (const float*)d_in[8], (const float*)d_in[10]};
    const float* linW  = (const float*)d_in[11];
    const float* linb  = (const float*)d_in[12];
    float* out = (float*)d_out;

    const int N  = in_sizes[2];
    const int E  = in_sizes[1] / 2;
    const int G  = out_size / 2;

    // carve workspace (256B-aligned slices)
    char* p = (char*)d_ws;
    auto carve = [&](size_t bytes) -> char* {
        char* r = p;
        p += (bytes + 255) & ~(size_t)255;
        return r;
    };
    int*   cnt    = (int*)  carve((size_t)N * 4);
    float* dinv   = (float*)carve((size_t)N * 4);
    int*   offs   = (int*)  carve((size_t)(N + 1) * 4);
    int*   cursor = (int*)  carve((size_t)(N + 1) * 4);
    int*   bsum   = (int*)  carve(512 * 4);
    int*   srcS   = (int*)  carve((size_t)(E + 4 * (size_t)N) * 4);   // padded CSR
    u32*   bufA   = (u32*)  carve((size_t)(N + 1) * NU * 4);   // bf16 ping (row N = 0)
    u32*   bufB   = (u32*)  carve((size_t)(N + 1) * NU * 4);   // bf16 pong (row N = 0)

    (void)hipMemsetAsync(cnt, 0, (size_t)N * 4, stream);
    k_deg<<<(E + 255) / 256, 256, 0, stream>>>(ei, cnt, E);

    int nb = (N + 1 + 255) / 256;   // covers items 0..N (item N has count 0)
    k_scan1<<<nb, 256, 0, stream>>>(cnt, dinv, offs, bsum, N);
    k_scan2<<<1, 512, 0, stream>>>(bsum, nb);
    k_scan3<<<nb, 256, 0, stream>>>(offs, bsum, cursor, N);

    int totalu4 = (N + 1) * (NU / 4);
    int prepT = totalu4 > E + N ? totalu4 : E + N;
    k_prep<<<(prepT + 255) / 256, 256, 0, stream>>>(ei, x, dinv, cnt, offs, cursor,
                                                    srcS, bufA, E, N);

    int ntiles = (N + 1 + TROWS - 1) / TROWS;
    int ngrid = ntiles < 2048 ? ntiles : 2048;
    const u32* hin = bufA;
    u32* hout = bufB;
    for (int l = 0; l < 4; ++l) {
        k_fused<<<ngrid, 256, 0, stream>>>(hin, offs, srcS, dinv, Wl[l], bl[l],
                                           hout, N, ntiles, l == 3);
        hin = hout;
        hout = (hout == bufA) ? bufB : bufA;
    }

    k_poolfinal<<<G, 256, 0, stream>>>(hin, batch, linW, linb, out, N);
}

// Round 9
// 747.428 us; speedup vs baseline: 1.3436x; 1.0364x over previous
//
#include <hip/hip_runtime.h>
#include <math.h>

#define NF 128      // feature/hidden dim (F == H == 128)
#define NU 64       // uints per bf16 row (NF/2)
#define TROWS 32    // fused-kernel tile rows
#define ARS 68      // As row stride in u32 (64 + 4 pad)
#define CRS 132     // Cs row stride in floats (128 + 4 pad)

typedef unsigned int  u32;
typedef unsigned short u16;
typedef u32 b4 __attribute__((ext_vector_type(2)));     // 4 bf16 (8B)
typedef short bf16x8 __attribute__((ext_vector_type(8)));  // MFMA A/B frag (16B)
typedef float f32x4 __attribute__((ext_vector_type(4)));   // MFMA C/D frag

__device__ inline u16 f2bf(float f) {               // RNE float->bf16
    u32 u = __float_as_uint(f);
    return (u16)((u + 0x7fffu + ((u >> 16) & 1u)) >> 16);
}
__device__ inline u32 pack2(float a, float b) {     // ch2k=lo, ch2k+1=hi
    return (u32)f2bf(a) | ((u32)f2bf(b) << 16);
}
__device__ inline float bflo(u32 u) { return __uint_as_float(u << 16); }
__device__ inline float bfhi(u32 u) { return __uint_as_float(u & 0xffff0000u); }

__device__ inline void nt_store_b4(u32* p, b4 v) {
    __builtin_nontemporal_store(v, (b4*)p);
}

// ---------- setup kernels ----------

__global__ void k_deg(const int* __restrict__ ei, int* cnt, int E) {
    int e = blockIdx.x * blockDim.x + threadIdx.x;
    if (e < E) atomicAdd(&cnt[ei[E + e]], 1);   // dst row; cnt = deg w/o self-loop
}

// Exclusive scan over PADDED counts vpad = roundup(cnt+1, 4); item n has v=0 so
// offs[n] lands automatically. Also emits dinv = rsqrt(real deg).
__global__ void k_scan1(const int* __restrict__ cnt, float* dinv,
                        int* offs, int* bsum, int n) {
    __shared__ int s[256];
    int t = threadIdx.x;
    int i = blockIdx.x * 256 + t;
    int v = 0;
    if (i < n) {
        int real = cnt[i] + 1;          // +1 self-loop
        dinv[i] = 1.0f / sqrtf((float)real);
        v = (real + 3) & ~3;            // pad row to multiple of 4
    }
    s[t] = v;
    for (int d = 1; d < 256; d <<= 1) {
        __syncthreads();
        int add = (t >= d) ? s[t - d] : 0;
        __syncthreads();
        s[t] += add;
    }
    __syncthreads();
    if (i <= n) offs[i] = s[t] - v;          // exclusive
    if (t == 255) bsum[blockIdx.x] = s[255]; // block total
}

__global__ void k_scan2(int* bsum, int nb) {
    __shared__ int s[512];
    int t = threadIdx.x;
    int v = (t < nb) ? bsum[t] : 0;
    s[t] = v;
    for (int d = 1; d < 512; d <<= 1) {
        __syncthreads();
        int add = (t >= d) ? s[t - d] : 0;
        __syncthreads();
        s[t] += add;
    }
    __syncthreads();
    if (t < nb) bsum[t] = s[t] - v;         // exclusive
}

__global__ void k_scan3(int* offs, const int* __restrict__ bsum, int* cursor, int n) {
    int i = blockIdx.x * 256 + threadIdx.x;
    if (i <= n) {
        int o = offs[i] + bsum[blockIdx.x];
        offs[i] = o;
        cursor[i] = o;
    }
}

// One prep kernel:
//  (a) q0[row] = bf16(dinv[row] * x[row])  (row n -> zeros; sentinel row)
//  (b) scatter real edges into padded dst-sorted CSR via atomic cursor,
//      self-loop + sentinel padding at row end
__global__ void k_prep(const int* __restrict__ ei, const float* __restrict__ x,
                       const float* __restrict__ dinv, const int* __restrict__ cnt,
                       const int* __restrict__ offs, int* cursor, int* srcS,
                       u32* __restrict__ q, int E, int n) {
    int t = blockIdx.x * blockDim.x + threadIdx.x;
    int totalu4 = (n + 1) * (NU / 4);     // 16 uint4 per row
    if (t < totalu4) {
        int row = t >> 4;
        uint4 o = make_uint4(0, 0, 0, 0);
        if (row < n) {
            int cbase = (t & 15) << 3;    // 8 channels per uint4
            const float* xr = x + (size_t)row * NF + cbase;
            float4 f0 = *(const float4*)(xr);
            float4 f1 = *(const float4*)(xr + 4);
            float d = dinv[row];
            o.x = pack2(f0.x * d, f0.y * d);
            o.y = pack2(f0.z * d, f0.w * d);
            o.z = pack2(f1.x * d, f1.y * d);
            o.w = pack2(f1.z * d, f1.w * d);
        }
        ((uint4*)q)[t] = o;
    }
    if (t < E) {
        int s = ei[t], d = ei[E + t];
        int p = atomicAdd(&cursor[d], 1);
        srcS[p] = s;
    } else if (t < E + n) {
        int i = t - E;
        int base = offs[i] + cnt[i];      // after the cnt[i] real edges
        srcS[base] = i;                   // self-loop
        int end = offs[i + 1];
        for (int k = base + 1; k < end; ++k) srcS[k] = n;   // sentinel padding
    }
}

// Build pre-swizzled bf16 B-fragments of the 4 weight matrices.
// Fragment (layer, nt, ks, lane) holds W[k][n] for n = nt*16 + (lane&15),
// k = ks*32 + (lane>>4)*8 + j, j=0..7 — packed as uint4 (8 bf16).
// Layout: uint4 index = layer*2048 + (nt*4 + ks)*64 + lane  -> coalesced 1KB
// loads per wave in the GEMM phase.
__global__ void k_wfrag(const float* __restrict__ W0, const float* __restrict__ W1,
                        const float* __restrict__ W2, const float* __restrict__ W3,
                        u32* __restrict__ wt) {
    int idx = blockIdx.x * blockDim.x + threadIdx.x;
    if (idx >= 4 * 2048) return;
    int layer = idx >> 11;
    int rem = idx & 2047;                 // = (nt*4+ks)*64 + lane
    int lane = rem & 63;
    int ks = (rem >> 6) & 3;
    int nt = rem >> 8;
    const float* W = layer == 0 ? W0 : layer == 1 ? W1 : layer == 2 ? W2 : W3;
    int n = nt * 16 + (lane & 15);
    int k0 = ks * 32 + (lane >> 4) * 8;
    uint4 o;
    o.x = pack2(W[(k0 + 0) * NF + n], W[(k0 + 1) * NF + n]);
    o.y = pack2(W[(k0 + 2) * NF + n], W[(k0 + 3) * NF + n]);
    o.z = pack2(W[(k0 + 4) * NF + n], W[(k0 + 5) * NF + n]);
    o.w = pack2(W[(k0 + 6) * NF + n], W[(k0 + 7) * NF + n]);
    ((uint4*)wt)[idx] = o;
}

// ---------- fused layer: bf16 gather-sum -> bf16 LDS tile -> MFMA GEMM -> epilogue ----------
// hin: bf16 q = dinv*h (row n zeros). agg[d] = dinv[d]*sum q[src] (fp32 acc,
// rounded to bf16 for MFMA A). Per tile: 4 waves, wave w computes C rows
// m0=(w&1)*16..+16, cols (w>>1)*64..+64 via 16 mfma_f32_16x16x32_bf16.
// LDS union: As bf16 (32 x ARS u32) aliased by Cs fp32 (32 x CRS) — barriers
// separate the phases.
__global__ __launch_bounds__(256, 8) void k_fused(
        const u32* __restrict__ hin, const int* __restrict__ offs,
        const int* __restrict__ srcS, const float* __restrict__ dinv,
        const u32* __restrict__ wt, const float* __restrict__ bias,
        u32* __restrict__ out, int n, int ntiles, int last) {
    __shared__ __align__(16) u32 buf[TROWS * CRS];   // 16.9 KB union As/Cs
    float* Cs = (float*)buf;
    int tid = threadIdx.x;
    int grp = tid >> 5;          // 0..7 (gather/epilogue groups)
    int lane32 = tid & 31;
    int c4 = lane32 << 2;        // channel offset (4 ch/lane)
    int cu = lane32 << 1;        // uint offset within bf16 row
    int wv = tid >> 6;           // wave 0..3 (MFMA phase)
    int lane = tid & 63;
    int m0 = (wv & 1) * 16;      // M-tile base row
    int nh = wv >> 1;            // N-half (cols nh*64..+64)
    int mrow = lane & 15, quad = lane >> 4;

    for (int tile = blockIdx.x; tile < ntiles; tile += gridDim.x) {
        int row0 = tile * TROWS;

        // ---- gather/sum phase (fp32 acc, bf16 As) ----
        #pragma unroll
        for (int i = 0; i < 4; ++i) {
            int r = grp * 4 + i;
            int node = row0 + r;
            float4 acc = make_float4(0.f, 0.f, 0.f, 0.f);
            if (node < n) {
                int b = offs[node], e = offs[node + 1];
                int j = b;
                for (; j + 8 <= e; j += 8) {
                    int4 sa = *(const int4*)(srcS + j);
                    int4 sb = *(const int4*)(srcS + j + 4);
                    b4 q0 = *(const b4*)(hin + (size_t)sa.x * NU + cu);
                    b4 q1 = *(const b4*)(hin + (size_t)sa.y * NU + cu);
                    b4 q2 = *(const b4*)(hin + (size_t)sa.z * NU + cu);
                    b4 q3 = *(const b4*)(hin + (size_t)sa.w * NU + cu);
                    b4 q4 = *(const b4*)(hin + (size_t)sb.x * NU + cu);
                    b4 q5 = *(const b4*)(hin + (size_t)sb.y * NU + cu);
                    b4 q6 = *(const b4*)(hin + (size_t)sb.z * NU + cu);
                    b4 q7 = *(const b4*)(hin + (size_t)sb.w * NU + cu);
                    acc.x += ((bflo(q0.x) + bflo(q1.x)) + (bflo(q2.x) + bflo(q3.x)))
                           + ((bflo(q4.x) + bflo(q5.x)) + (bflo(q6.x) + bflo(q7.x)));
                    acc.y += ((bfhi(q0.x) + bfhi(q1.x)) + (bfhi(q2.x) + bfhi(q3.x)))
                           + ((bfhi(q4.x) + bfhi(q5.x)) + (bfhi(q6.x) + bfhi(q7.x)));
                    acc.z += ((bflo(q0.y) + bflo(q1.y)) + (bflo(q2.y) + bflo(q3.y)))
                           + ((bflo(q4.y) + bflo(q5.y)) + (bflo(q6.y) + bflo(q7.y)));
                    acc.w += ((bfhi(q0.y) + bfhi(q1.y)) + (bfhi(q2.y) + bfhi(q3.y)))
                           + ((bfhi(q4.y) + bfhi(q5.y)) + (bfhi(q6.y) + bfhi(q7.y)));
                }
                if (j < e) {                 // exactly 4 remain (count % 8 == 4)
                    int4 sa = *(const int4*)(srcS + j);
                    b4 q0 = *(const b4*)(hin + (size_t)sa.x * NU + cu);
                    b4 q1 = *(const b4*)(hin + (size_t)sa.y * NU + cu);
                    b4 q2 = *(const b4*)(hin + (size_t)sa.z * NU + cu);
                    b4 q3 = *(const b4*)(hin + (size_t)sa.w * NU + cu);
                    acc.x += (bflo(q0.x) + bflo(q1.x)) + (bflo(q2.x) + bflo(q3.x));
                    acc.y += (bfhi(q0.x) + bfhi(q1.x)) + (bfhi(q2.x) + bfhi(q3.x));
                    acc.z += (bflo(q0.y) + bflo(q1.y)) + (bflo(q2.y) + bflo(q3.y));
                    acc.w += (bfhi(q0.y) + bfhi(q1.y)) + (bfhi(q2.y) + bfhi(q3.y));
                }
                float dn = dinv[node];
                acc.x *= dn; acc.y *= dn; acc.z *= dn; acc.w *= dn;
            }
            b4 o; o.x = pack2(acc.x, acc.y); o.y = pack2(acc.z, acc.w);
            *(b4*)(buf + r * ARS + cu) = o;
        }
        __syncthreads();

        // ---- MFMA GEMM phase ----
        f32x4 a0 = {0.f, 0.f, 0.f, 0.f}, a1 = a0, a2 = a0, a3 = a0;
        #pragma unroll
        for (int ks = 0; ks < 4; ++ks) {
            bf16x8 a = *(const bf16x8*)(buf + (m0 + mrow) * ARS + ks * 16 + quad * 4);
            const u32* wb = wt + (((nh * 4) * 4 + ks) * 64 + lane) * 4;
            bf16x8 b0 = *(const bf16x8*)(wb);
            bf16x8 b1 = *(const bf16x8*)(wb + 1024);   // nt+1 -> +256 uint4
            bf16x8 b2 = *(const bf16x8*)(wb + 2048);
            bf16x8 b3 = *(const bf16x8*)(wb + 3072);
            a0 = __builtin_amdgcn_mfma_f32_16x16x32_bf16(a, b0, a0, 0, 0, 0);
            a1 = __builtin_amdgcn_mfma_f32_16x16x32_bf16(a, b1, a1, 0, 0, 0);
            a2 = __builtin_amdgcn_mfma_f32_16x16x32_bf16(a, b2, a2, 0, 0, 0);
            a3 = __builtin_amdgcn_mfma_f32_16x16x32_bf16(a, b3, a3, 0, 0, 0);
        }
        __syncthreads();   // all As reads done before Cs overwrites the union

        // C frags -> LDS (col = lane&15, row = quad*4+reg; stride 132 -> 2-way max)
        #pragma unroll
        for (int nt = 0; nt < 4; ++nt) {
            f32x4 av = nt == 0 ? a0 : nt == 1 ? a1 : nt == 2 ? a2 : a3;
            int col = (nh * 4 + nt) * 16 + mrow;
            #pragma unroll
            for (int rg = 0; rg < 4; ++rg)
                Cs[(m0 + quad * 4 + rg) * CRS + col] = av[rg];
        }
        __syncthreads();

        // ---- epilogue: bias + ReLU (+ dinv rescale), pack bf16, NT store ----
        float4 bv = *(const float4*)(bias + c4);
        #pragma unroll
        for (int j = 0; j < 4; ++j) {
            int r = grp * 4 + j;
            int gr = row0 + r;
            if (gr <= n) {
                b4 o; o.x = 0u; o.y = 0u;
                if (gr < n) {
                    float4 v = *(const float4*)(Cs + r * CRS + c4);
                    float sc = last ? 1.0f : dinv[gr];
                    float ox = fmaxf(v.x + bv.x, 0.f) * sc;
                    float oy = fmaxf(v.y + bv.y, 0.f) * sc;
                    float oz = fmaxf(v.z + bv.z, 0.f) * sc;
                    float ow = fmaxf(v.w + bv.w, 0.f) * sc;
                    o.x = pack2(ox, oy);
                    o.y = pack2(oz, ow);
                }
                nt_store_b4(out + (size_t)gr * NU + cu, o);   // gr==n keeps sentinel 0
            }
        }
        __syncthreads();   // buf reused as As next tile
    }
}

// ---------- fused pool + head (batch sorted -> contiguous ranges; bounds inline) ----------

__global__ __launch_bounds__(256) void k_poolfinal(const u32* __restrict__ h,
        const int* __restrict__ batch, const float* __restrict__ linW,
        const float* __restrict__ linb, float* __restrict__ outp, int N) {
    int g = blockIdx.x;
    int tid = threadIdx.x;
    __shared__ int sb[2];
    if (tid < 2) {                       // lower_bound(batch, g+tid)
        int target = g + tid;
        int lo = 0, hi = N;
        while (lo < hi) {
            int mid = (lo + hi) >> 1;
            if (batch[mid] < target) lo = mid + 1; else hi = mid;
        }
        sb[tid] = lo;
    }
    __syncthreads();
    int b = sb[0], e = sb[1];

    int grp = tid >> 5, lane = tid & 31;
    int c4 = lane << 2, cu = lane << 1;
    float4 acc = make_float4(0.f, 0.f, 0.f, 0.f);
    for (int i = b + grp; i < e; i += 8) {
        b4 v = *(const b4*)(h + (size_t)i * NU + cu);
        acc.x += bflo(v.x); acc.y += bfhi(v.x);
        acc.z += bflo(v.y); acc.w += bfhi(v.y);
    }
    __shared__ float red[8][NF];
    *(float4*)(&red[grp][c4]) = acc;
    __syncthreads();

    float v0 = 0.f, v1 = 0.f;
    if (tid < NF) {
        float s = 0.f;
        #pragma unroll
        for (int gg = 0; gg < 8; ++gg) s += red[gg][tid];
        v0 = s * linW[tid * 2 + 0];
        v1 = s * linW[tid * 2 + 1];
    }
    #pragma unroll
    for (int d = 32; d > 0; d >>= 1) {
        v0 += __shfl_down(v0, d);
        v1 += __shfl_down(v1, d);
    }
    __shared__ float sv[8];
    if ((tid & 63) == 0) { sv[(tid >> 6) * 2] = v0; sv[(tid >> 6) * 2 + 1] = v1; }
    __syncthreads();
    if (tid == 0) {
        float inv = 1.0f / fmaxf((float)(e - b), 1.0f);
        outp[g * 2 + 0] = (sv[0] + sv[2]) * inv + linb[0];
        outp[g * 2 + 1] = (sv[1] + sv[3]) * inv + linb[1];
    }
}

// ---------- launcher ----------

extern "C" void kernel_launch(void* const* d_in, const int* in_sizes, int n_in,
                              void* d_out, int out_size, void* d_ws, size_t ws_size,
                              hipStream_t stream) {
    const float* x     = (const float*)d_in[0];
    const int*   ei    = (const int*)d_in[1];
    const int*   batch = (const int*)d_in[2];
    const float* Wl[4] = {(const float*)d_in[3], (const float*)d_in[5],
                          (const float*)d_in[7], (const float*)d_in[9]};
    const float* bl[4] = {(const float*)d_in[4], (const float*)d_in[6],
                          (const float*)d_in[8], (const float*)d_in[10]};
    const float* linW  = (const float*)d_in[11];
    const float* linb  = (const float*)d_in[12];
    float* out = (float*)d_out;

    const int N  = in_sizes[2];
    const int E  = in_sizes[1] / 2;
    const int G  = out_size / 2;

    // carve workspace (256B-aligned slices)
    char* p = (char*)d_ws;
    auto carve = [&](size_t bytes) -> char* {
        char* r = p;
        p += (bytes + 255) & ~(size_t)255;
        return r;
    };
    int*   cnt    = (int*)  carve((size_t)N * 4);
    float* dinv   = (float*)carve((size_t)N * 4);
    int*   offs   = (int*)  carve((size_t)(N + 1) * 4);
    int*   cursor = (int*)  carve((size_t)(N + 1) * 4);
    int*   bsum   = (int*)  carve(512 * 4);
    u32*   wt     = (u32*)  carve(4 * 2048 * 16);              // bf16 W fragments
    int*   srcS   = (int*)  carve((size_t)(E + 4 * (size_t)N) * 4);   // padded CSR
    u32*   bufA   = (u32*)  carve((size_t)(N + 1) * NU * 4);   // bf16 ping (row N = 0)
    u32*   bufB   = (u32*)  carve((size_t)(N + 1) * NU * 4);   // bf16 pong (row N = 0)

    (void)hipMemsetAsync(cnt, 0, (size_t)N * 4, stream);
    k_deg<<<(E + 255) / 256, 256, 0, stream>>>(ei, cnt, E);

    int nb = (N + 1 + 255) / 256;   // covers items 0..N (item N has count 0)
    k_scan1<<<nb, 256, 0, stream>>>(cnt, dinv, offs, bsum, N);
    k_scan2<<<1, 512, 0, stream>>>(bsum, nb);
    k_scan3<<<nb, 256, 0, stream>>>(offs, bsum, cursor, N);

    k_wfrag<<<32, 256, 0, stream>>>(Wl[0], Wl[1], Wl[2], Wl[3], wt);

    int totalu4 = (N + 1) * (NU / 4);
    int prepT = totalu4 > E + N ? totalu4 : E + N;
    k_prep<<<(prepT + 255) / 256, 256, 0, stream>>>(ei, x, dinv, cnt, offs, cursor,
                                                    srcS, bufA, E, N);

    int ntiles = (N + 1 + TROWS - 1) / TROWS;
    int k = (ntiles + 2047) / 2048;                 // tiles per block
    int ngrid = (ntiles + k - 1) / k;               // 1563 for N=100000 -> exact 2x
    const u32* hin = bufA;
    u32* hout = bufB;
    for (int l = 0; l < 4; ++l) {
        k_fused<<<ngrid, 256, 0, stream>>>(hin, offs, srcS, dinv, wt + l * 8192,
                                           bl[l], hout, N, ntiles, l == 3);
        hin = hout;
        hout = (hout == bufA) ? bufB : bufA;
    }

    k_poolfinal<<<G, 256, 0, stream>>>(hin, batch, linW, linb, out, N);
}

// Round 10
// 722.675 us; speedup vs baseline: 1.3896x; 1.0343x over previous
//
#include <hip/hip_runtime.h>
#include <math.h>

#define NF 128      // feature/hidden dim (F == H == 128)
#define NU 64       // uints per bf16 row (NF/2)
#define TROWS 32    // fused-kernel tile rows
#define ARS 68      // As row stride in u32 (64 + 4 pad)
#define CRS 132     // Cs row stride in floats (128 + 4 pad)

typedef unsigned int  u32;
typedef unsigned short u16;
typedef u32 b4 __attribute__((ext_vector_type(2)));     // 4 bf16 (8B)
typedef short bf16x8 __attribute__((ext_vector_type(8)));  // MFMA A/B frag (16B)
typedef float f32x4 __attribute__((ext_vector_type(4)));   // MFMA C/D frag

__device__ inline u16 f2bf(float f) {               // RNE float->bf16
    u32 u = __float_as_uint(f);
    return (u16)((u + 0x7fffu + ((u >> 16) & 1u)) >> 16);
}
__device__ inline u32 pack2(float a, float b) {     // ch2k=lo, ch2k+1=hi
    return (u32)f2bf(a) | ((u32)f2bf(b) << 16);
}
__device__ inline float bflo(u32 u) { return __uint_as_float(u << 16); }
__device__ inline float bfhi(u32 u) { return __uint_as_float(u & 0xffff0000u); }

// ---------- setup kernels ----------

__global__ void k_deg(const int* __restrict__ ei, int* cnt, int E) {
    int e = blockIdx.x * blockDim.x + threadIdx.x;
    if (e < E) atomicAdd(&cnt[ei[E + e]], 1);   // dst row; cnt = deg w/o self-loop
}

// Exclusive scan over PADDED counts vpad = roundup(cnt+1, 4); item n has v=0 so
// offs[n] lands automatically. Also emits dinv = rsqrt(real deg).
__global__ void k_scan1(const int* __restrict__ cnt, float* dinv,
                        int* offs, int* bsum, int n) {
    __shared__ int s[256];
    int t = threadIdx.x;
    int i = blockIdx.x * 256 + t;
    int v = 0;
    if (i < n) {
        int real = cnt[i] + 1;          // +1 self-loop
        dinv[i] = 1.0f / sqrtf((float)real);
        v = (real + 3) & ~3;            // pad row to multiple of 4
    }
    s[t] = v;
    for (int d = 1; d < 256; d <<= 1) {
        __syncthreads();
        int add = (t >= d) ? s[t - d] : 0;
        __syncthreads();
        s[t] += add;
    }
    __syncthreads();
    if (i <= n) offs[i] = s[t] - v;          // exclusive
    if (t == 255) bsum[blockIdx.x] = s[255]; // block total
}

__global__ void k_scan2(int* bsum, int nb) {
    __shared__ int s[512];
    int t = threadIdx.x;
    int v = (t < nb) ? bsum[t] : 0;
    s[t] = v;
    for (int d = 1; d < 512; d <<= 1) {
        __syncthreads();
        int add = (t >= d) ? s[t - d] : 0;
        __syncthreads();
        s[t] += add;
    }
    __syncthreads();
    if (t < nb) bsum[t] = s[t] - v;         // exclusive
}

__global__ void k_scan3(int* offs, const int* __restrict__ bsum, int* cursor, int n) {
    int i = blockIdx.x * 256 + threadIdx.x;
    if (i <= n) {
        int o = offs[i] + bsum[blockIdx.x];
        offs[i] = o;
        cursor[i] = o;
    }
}

// One prep kernel:
//  (a) q0[row] = bf16(dinv[row] * x[row])  (row n -> zeros; sentinel row)
//  (b) scatter real edges into padded dst-sorted CSR via atomic cursor,
//      self-loop + sentinel padding at row end
//  (c) t < 8192: build pre-swizzled bf16 B-fragments of the 4 weight matrices.
//      Fragment (layer, nt, ks, lane) holds W[k][n], n = nt*16 + (lane&15),
//      k = ks*32 + (lane>>4)*8 + j (j=0..7), packed uint4; index =
//      layer*2048 + (nt*4+ks)*64 + lane -> coalesced 1KB loads per wave.
__global__ void k_prep(const int* __restrict__ ei, const float* __restrict__ x,
                       const float* __restrict__ dinv, const int* __restrict__ cnt,
                       const int* __restrict__ offs, int* cursor, int* srcS,
                       u32* __restrict__ q,
                       const float* __restrict__ W0, const float* __restrict__ W1,
                       const float* __restrict__ W2, const float* __restrict__ W3,
                       u32* __restrict__ wt, int E, int n) {
    int t = blockIdx.x * blockDim.x + threadIdx.x;
    int totalu4 = (n + 1) * (NU / 4);     // 16 uint4 per row
    if (t < totalu4) {
        int row = t >> 4;
        uint4 o = make_uint4(0, 0, 0, 0);
        if (row < n) {
            int cbase = (t & 15) << 3;    // 8 channels per uint4
            const float* xr = x + (size_t)row * NF + cbase;
            float4 f0 = *(const float4*)(xr);
            float4 f1 = *(const float4*)(xr + 4);
            float d = dinv[row];
            o.x = pack2(f0.x * d, f0.y * d);
            o.y = pack2(f0.z * d, f0.w * d);
            o.z = pack2(f1.x * d, f1.y * d);
            o.w = pack2(f1.z * d, f1.w * d);
        }
        ((uint4*)q)[t] = o;
    }
    if (t < E) {
        int s = ei[t], d = ei[E + t];
        int p = atomicAdd(&cursor[d], 1);
        srcS[p] = s;
    } else if (t < E + n) {
        int i = t - E;
        int base = offs[i] + cnt[i];      // after the cnt[i] real edges
        srcS[base] = i;                   // self-loop
        int end = offs[i + 1];
        for (int k = base + 1; k < end; ++k) srcS[k] = n;   // sentinel padding
    }
    if (t < 4 * 2048) {
        int layer = t >> 11;
        int rem = t & 2047;               // = (nt*4+ks)*64 + lane
        int lane = rem & 63;
        int ks = (rem >> 6) & 3;
        int nt = rem >> 8;
        const float* W = layer == 0 ? W0 : layer == 1 ? W1 : layer == 2 ? W2 : W3;
        int nn = nt * 16 + (lane & 15);
        int k0 = ks * 32 + (lane >> 4) * 8;
        uint4 o;
        o.x = pack2(W[(k0 + 0) * NF + nn], W[(k0 + 1) * NF + nn]);
        o.y = pack2(W[(k0 + 2) * NF + nn], W[(k0 + 3) * NF + nn]);
        o.z = pack2(W[(k0 + 4) * NF + nn], W[(k0 + 5) * NF + nn]);
        o.w = pack2(W[(k0 + 6) * NF + nn], W[(k0 + 7) * NF + nn]);
        ((uint4*)wt)[t] = o;
    }
}

// ---------- fused layer: bf16 gather-sum -> bf16 LDS tile -> MFMA GEMM -> epilogue ----------
// hin: bf16 q = dinv*h (row n zeros). agg[d] = dinv[d]*sum q[src] (fp32 acc,
// rounded to bf16 for MFMA A). Per tile: 4 waves, wave w computes C rows
// m0=(w&1)*16..+16, cols (w>>1)*64..+64 via 16 mfma_f32_16x16x32_bf16.
// LDS union: As bf16 (32 x ARS u32) aliased by Cs fp32 (32 x CRS) — barriers
// separate the phases. h stored with PLAIN stores (L2/L3-resident for the
// next layer's gather — NT stores here cost ~80MB/layer of HBM refetch).
__global__ __launch_bounds__(256, 8) void k_fused(
        const u32* __restrict__ hin, const int* __restrict__ offs,
        const int* __restrict__ srcS, const float* __restrict__ dinv,
        const u32* __restrict__ wt, const float* __restrict__ bias,
        u32* __restrict__ out, int n, int ntiles, int last) {
    __shared__ __align__(16) u32 buf[TROWS * CRS];   // 16.9 KB union As/Cs
    float* Cs = (float*)buf;
    int tid = threadIdx.x;
    int grp = tid >> 5;          // 0..7 (gather/epilogue groups)
    int lane32 = tid & 31;
    int c4 = lane32 << 2;        // channel offset (4 ch/lane)
    int cu = lane32 << 1;        // uint offset within bf16 row
    int wv = tid >> 6;           // wave 0..3 (MFMA phase)
    int lane = tid & 63;
    int m0 = (wv & 1) * 16;      // M-tile base row
    int nh = wv >> 1;            // N-half (cols nh*64..+64)
    int mrow = lane & 15, quad = lane >> 4;

    float4 bv = *(const float4*)(bias + c4);   // constant across tiles

    for (int tile = blockIdx.x; tile < ntiles; tile += gridDim.x) {
        int row0 = tile * TROWS;

        // ---- gather/sum phase (fp32 acc, bf16 As) ----
        #pragma unroll
        for (int i = 0; i < 4; ++i) {
            int r = grp * 4 + i;
            int node = row0 + r;
            float4 acc = make_float4(0.f, 0.f, 0.f, 0.f);
            if (node < n) {
                int b = offs[node], e = offs[node + 1];
                int j = b;
                for (; j + 8 <= e; j += 8) {
                    int4 sa = *(const int4*)(srcS + j);
                    int4 sb = *(const int4*)(srcS + j + 4);
                    b4 q0 = *(const b4*)(hin + (size_t)sa.x * NU + cu);
                    b4 q1 = *(const b4*)(hin + (size_t)sa.y * NU + cu);
                    b4 q2 = *(const b4*)(hin + (size_t)sa.z * NU + cu);
                    b4 q3 = *(const b4*)(hin + (size_t)sa.w * NU + cu);
                    b4 q4 = *(const b4*)(hin + (size_t)sb.x * NU + cu);
                    b4 q5 = *(const b4*)(hin + (size_t)sb.y * NU + cu);
                    b4 q6 = *(const b4*)(hin + (size_t)sb.z * NU + cu);
                    b4 q7 = *(const b4*)(hin + (size_t)sb.w * NU + cu);
                    acc.x += ((bflo(q0.x) + bflo(q1.x)) + (bflo(q2.x) + bflo(q3.x)))
                           + ((bflo(q4.x) + bflo(q5.x)) + (bflo(q6.x) + bflo(q7.x)));
                    acc.y += ((bfhi(q0.x) + bfhi(q1.x)) + (bfhi(q2.x) + bfhi(q3.x)))
                           + ((bfhi(q4.x) + bfhi(q5.x)) + (bfhi(q6.x) + bfhi(q7.x)));
                    acc.z += ((bflo(q0.y) + bflo(q1.y)) + (bflo(q2.y) + bflo(q3.y)))
                           + ((bflo(q4.y) + bflo(q5.y)) + (bflo(q6.y) + bflo(q7.y)));
                    acc.w += ((bfhi(q0.y) + bfhi(q1.y)) + (bfhi(q2.y) + bfhi(q3.y)))
                           + ((bfhi(q4.y) + bfhi(q5.y)) + (bfhi(q6.y) + bfhi(q7.y)));
                }
                if (j < e) {                 // exactly 4 remain (count % 8 == 4)
                    int4 sa = *(const int4*)(srcS + j);
                    b4 q0 = *(const b4*)(hin + (size_t)sa.x * NU + cu);
                    b4 q1 = *(const b4*)(hin + (size_t)sa.y * NU + cu);
                    b4 q2 = *(const b4*)(hin + (size_t)sa.z * NU + cu);
                    b4 q3 = *(const b4*)(hin + (size_t)sa.w * NU + cu);
                    acc.x += (bflo(q0.x) + bflo(q1.x)) + (bflo(q2.x) + bflo(q3.x));
                    acc.y += (bfhi(q0.x) + bfhi(q1.x)) + (bfhi(q2.x) + bfhi(q3.x));
                    acc.z += (bflo(q0.y) + bflo(q1.y)) + (bflo(q2.y) + bflo(q3.y));
                    acc.w += (bfhi(q0.y) + bfhi(q1.y)) + (bfhi(q2.y) + bfhi(q3.y));
                }
                float dn = dinv[node];
                acc.x *= dn; acc.y *= dn; acc.z *= dn; acc.w *= dn;
            }
            b4 o; o.x = pack2(acc.x, acc.y); o.y = pack2(acc.z, acc.w);
            *(b4*)(buf + r * ARS + cu) = o;
        }
        __syncthreads();

        // ---- MFMA GEMM phase ----
        f32x4 a0 = {0.f, 0.f, 0.f, 0.f}, a1 = a0, a2 = a0, a3 = a0;
        #pragma unroll
        for (int ks = 0; ks < 4; ++ks) {
            bf16x8 a = *(const bf16x8*)(buf + (m0 + mrow) * ARS + ks * 16 + quad * 4);
            const u32* wb = wt + (((nh * 4) * 4 + ks) * 64 + lane) * 4;
            bf16x8 b0 = *(const bf16x8*)(wb);
            bf16x8 b1 = *(const bf16x8*)(wb + 1024);   // nt+1 -> +256 uint4
            bf16x8 b2 = *(const bf16x8*)(wb + 2048);
            bf16x8 b3 = *(const bf16x8*)(wb + 3072);
            a0 = __builtin_amdgcn_mfma_f32_16x16x32_bf16(a, b0, a0, 0, 0, 0);
            a1 = __builtin_amdgcn_mfma_f32_16x16x32_bf16(a, b1, a1, 0, 0, 0);
            a2 = __builtin_amdgcn_mfma_f32_16x16x32_bf16(a, b2, a2, 0, 0, 0);
            a3 = __builtin_amdgcn_mfma_f32_16x16x32_bf16(a, b3, a3, 0, 0, 0);
        }
        __syncthreads();   // all As reads done before Cs overwrites the union

        // C frags -> LDS (col = lane&15, row = quad*4+reg)
        #pragma unroll
        for (int nt = 0; nt < 4; ++nt) {
            f32x4 av = nt == 0 ? a0 : nt == 1 ? a1 : nt == 2 ? a2 : a3;
            int col = (nh * 4 + nt) * 16 + mrow;
            #pragma unroll
            for (int rg = 0; rg < 4; ++rg)
                Cs[(m0 + quad * 4 + rg) * CRS + col] = av[rg];
        }
        __syncthreads();

        // ---- epilogue: bias + ReLU (+ dinv rescale), pack bf16, plain store ----
        #pragma unroll
        for (int j = 0; j < 4; ++j) {
            int r = grp * 4 + j;
            int gr = row0 + r;
            if (gr <= n) {
                b4 o; o.x = 0u; o.y = 0u;
                if (gr < n) {
                    float4 v = *(const float4*)(Cs + r * CRS + c4);
                    float sc = last ? 1.0f : dinv[gr];
                    float ox = fmaxf(v.x + bv.x, 0.f) * sc;
                    float oy = fmaxf(v.y + bv.y, 0.f) * sc;
                    float oz = fmaxf(v.z + bv.z, 0.f) * sc;
                    float ow = fmaxf(v.w + bv.w, 0.f) * sc;
                    o.x = pack2(ox, oy);
                    o.y = pack2(oz, ow);
                }
                *(b4*)(out + (size_t)gr * NU + cu) = o;   // gr==n keeps sentinel 0
            }
        }
        __syncthreads();   // buf reused as As next tile
    }
}

// ---------- fused pool + head (batch sorted -> contiguous ranges; bounds inline) ----------

__global__ __launch_bounds__(256) void k_poolfinal(const u32* __restrict__ h,
        const int* __restrict__ batch, const float* __restrict__ linW,
        const float* __restrict__ linb, float* __restrict__ outp, int N) {
    int g = blockIdx.x;
    int tid = threadIdx.x;
    __shared__ int sb[2];
    if (tid < 2) {                       // lower_bound(batch, g+tid)
        int target = g + tid;
        int lo = 0, hi = N;
        while (lo < hi) {
            int mid = (lo + hi) >> 1;
            if (batch[mid] < target) lo = mid + 1; else hi = mid;
        }
        sb[tid] = lo;
    }
    __syncthreads();
    int b = sb[0], e = sb[1];

    int grp = tid >> 5, lane = tid & 31;
    int c4 = lane << 2, cu = lane << 1;
    float4 acc = make_float4(0.f, 0.f, 0.f, 0.f);
    for (int i = b + grp; i < e; i += 8) {
        b4 v = *(const b4*)(h + (size_t)i * NU + cu);
        acc.x += bflo(v.x); acc.y += bfhi(v.x);
        acc.z += bflo(v.y); acc.w += bfhi(v.y);
    }
    __shared__ float red[8][NF];
    *(float4*)(&red[grp][c4]) = acc;
    __syncthreads();

    float v0 = 0.f, v1 = 0.f;
    if (tid < NF) {
        float s = 0.f;
        #pragma unroll
        for (int gg = 0; gg < 8; ++gg) s += red[gg][tid];
        v0 = s * linW[tid * 2 + 0];
        v1 = s * linW[tid * 2 + 1];
    }
    #pragma unroll
    for (int d = 32; d > 0; d >>= 1) {
        v0 += __shfl_down(v0, d);
        v1 += __shfl_down(v1, d);
    }
    __shared__ float sv[8];
    if ((tid & 63) == 0) { sv[(tid >> 6) * 2] = v0; sv[(tid >> 6) * 2 + 1] = v1; }
    __syncthreads();
    if (tid == 0) {
        float inv = 1.0f / fmaxf((float)(e - b), 1.0f);
        outp[g * 2 + 0] = (sv[0] + sv[2]) * inv + linb[0];
        outp[g * 2 + 1] = (sv[1] + sv[3]) * inv + linb[1];
    }
}

// ---------- launcher ----------

extern "C" void kernel_launch(void* const* d_in, const int* in_sizes, int n_in,
                              void* d_out, int out_size, void* d_ws, size_t ws_size,
                              hipStream_t stream) {
    const float* x     = (const float*)d_in[0];
    const int*   ei    = (const int*)d_in[1];
    const int*   batch = (const int*)d_in[2];
    const float* Wl[4] = {(const float*)d_in[3], (const float*)d_in[5],
                          (const float*)d_in[7], (const float*)d_in[9]};
    const float* bl[4] = {(const float*)d_in[4], (const float*)d_in[6],
                          (const float*)d_in[8], (const float*)d_in[10]};
    const float* linW  = (const float*)d_in[11];
    const float* linb  = (const float*)d_in[12];
    float* out = (float*)d_out;

    const int N  = in_sizes[2];
    const int E  = in_sizes[1] / 2;
    const int G  = out_size / 2;

    // carve workspace (256B-aligned slices)
    char* p = (char*)d_ws;
    auto carve = [&](size_t bytes) -> char* {
        char* r = p;
        p += (bytes + 255) & ~(size_t)255;
        return r;
    };
    int*   cnt    = (int*)  carve((size_t)N * 4);
    float* dinv   = (float*)carve((size_t)N * 4);
    int*   offs   = (int*)  carve((size_t)(N + 1) * 4);
    int*   cursor = (int*)  carve((size_t)(N + 1) * 4);
    int*   bsum   = (int*)  carve(512 * 4);
    u32*   wt     = (u32*)  carve(4 * 2048 * 16);              // bf16 W fragments
    int*   srcS   = (int*)  carve((size_t)(E + 4 * (size_t)N) * 4);   // padded CSR
    u32*   bufA   = (u32*)  carve((size_t)(N + 1) * NU * 4);   // bf16 ping (row N = 0)
    u32*   bufB   = (u32*)  carve((size_t)(N + 1) * NU * 4);   // bf16 pong (row N = 0)

    (void)hipMemsetAsync(cnt, 0, (size_t)N * 4, stream);
    k_deg<<<(E + 255) / 256, 256, 0, stream>>>(ei, cnt, E);

    int nb = (N + 1 + 255) / 256;   // covers items 0..N (item N has count 0)
    k_scan1<<<nb, 256, 0, stream>>>(cnt, dinv, offs, bsum, N);
    k_scan2<<<1, 512, 0, stream>>>(bsum, nb);
    k_scan3<<<nb, 256, 0, stream>>>(offs, bsum, cursor, N);

    int totalu4 = (N + 1) * (NU / 4);
    int prepT = totalu4 > E + N ? totalu4 : E + N;
    k_prep<<<(prepT + 255) / 256, 256, 0, stream>>>(ei, x, dinv, cnt, offs, cursor,
                                                    srcS, bufA,
                                                    Wl[0], Wl[1], Wl[2], Wl[3], wt,
                                                    E, N);

    int ntiles = (N + 1 + TROWS - 1) / TROWS;
    int k = (ntiles + 2047) / 2048;                 // tiles per block
    int ngrid = (ntiles + k - 1) / k;               // 1563 for N=100000 -> exact 2x
    const u32* hin = bufA;
    u32* hout = bufB;
    for (int l = 0; l < 4; ++l) {
        k_fused<<<ngrid, 256, 0, stream>>>(hin, offs, srcS, dinv, wt + l * 8192,
                                           bl[l], hout, N, ntiles, l == 3);
        hin = hout;
        hout = (hout == bufA) ? bufB : bufA;
    }

    k_poolfinal<<<G, 256, 0, stream>>>(hin, batch, linW, linb, out, N);
}